// Round 16
// baseline (114.753 us; speedup 1.0000x reference)
//
#include <hip/hip_runtime.h>
#include <stdint.h>

#define T_TOK 8192   // B*S
#define DD    1024   // D
#define EN    8      // experts
#define CPAD  16     // ints per expert counter slot (64 B each)

#define BM 256
#define BN 256
#define BK 64
#define NT (DD / BK)   // 16 K-steps
#define NWG 1024       // 8 experts * 32 M-slots * 4 N-tiles (early-exit), ~1 live/CU

#define GATE_NB 512    // gate blocks (16 tokens each)

#define AS1 __attribute__((address_space(1)))
#define AS3 __attribute__((address_space(3)))

typedef __bf16 v8bf __attribute__((ext_vector_type(8)));
typedef float  v4f  __attribute__((ext_vector_type(4)));

__device__ __forceinline__ uint16_t f2b(float f) {
  uint32_t u = __builtin_bit_cast(uint32_t, f);
  u += 0x7FFFu + ((u >> 16) & 1u);          // round-to-nearest-even
  return (uint16_t)(u >> 16);
}
__device__ __forceinline__ float b2f(uint16_t h) {
  uint32_t u = (uint32_t)h << 16;
  return __builtin_bit_cast(float, u);
}

// ---------- Phase 1 (fused): gate blocks [0,512), transpose [512,2560) — R15-identical ----------
template <bool WRITE_PIDX>
__global__ __launch_bounds__(256) void prep_kernel(
    const float* __restrict__ x, const float* __restrict__ gw,
    const float* __restrict__ gb, uint16_t* __restrict__ xb,
    int* __restrict__ counts, int* __restrict__ lists, int* __restrict__ pidx,
    const float* __restrict__ w, uint16_t* __restrict__ wt) {
  extern __shared__ __align__(16) uint8_t smem[];
  const int bid = blockIdx.x;
  const int tid = threadIdx.x;

  if (bid >= GATE_NB) {             // ---- transpose part ----
    float (*tile)[65] = (float(*)[65])smem;   // 16.6 KB
    const int tb = bid - GATE_NB;
    const int e = tb >> 8;
    const int rem = tb & 255;
    const int f0 = (rem & 15) * 64, d0 = (rem >> 4) * 64;
    const float* wsrc = w + ((size_t)e << 20);
    uint16_t* wdst = wt + ((size_t)e << 20);
    const int r4 = tid >> 4;          // 0..15
    const int c4 = (tid & 15) * 4;    // 0,4,...,60
#pragma unroll
    for (int i = 0; i < 4; ++i) {
      int row = i * 16 + r4;
      const float4 v = *(const float4*)(wsrc + (size_t)(d0 + row) * DD + f0 + c4);
      tile[row][c4 + 0] = v.x; tile[row][c4 + 1] = v.y;
      tile[row][c4 + 2] = v.z; tile[row][c4 + 3] = v.w;
    }
    __syncthreads();
#pragma unroll
    for (int i = 0; i < 4; ++i) {
      int f = i * 16 + r4;
      ushort4 h;
      h.x = f2b(tile[c4 + 0][f]); h.y = f2b(tile[c4 + 1][f]);
      h.z = f2b(tile[c4 + 2][f]); h.w = f2b(tile[c4 + 3][f]);
      *(ushort4*)(wdst + (size_t)(f0 + f) * DD + d0 + c4) = h;
    }
    return;
  }

  // ---- gate part: 16 tokens per block, 4 per wave ----
  float* sgwt = (float*)smem;                      // 32 KB, transposed [e][1024]
  float (*sx)[DD] = (float(*)[DD])(smem + 32768);  // 16 KB, one token per wave
  int* se1 = (int*)(smem + 49152);                 // 16 ints
  int* se2 = (int*)(smem + 49152 + 64);

#pragma unroll
  for (int i = 0; i < 8; ++i) {
    const int j4 = i * 256 + tid;
    const float4 v = ((const float4*)gw)[j4];
    const int d = j4 >> 1;
    const int e0 = (j4 & 1) * 4;
    sgwt[(e0 + 0) * DD + d] = v.x;
    sgwt[(e0 + 1) * DD + d] = v.y;
    sgwt[(e0 + 2) * DD + d] = v.z;
    sgwt[(e0 + 3) * DD + d] = v.w;
  }
  __syncthreads();

  const int t0 = bid * 16;
  const int wid = tid >> 6, lane = tid & 63;

  for (int r = 0; r < 4; ++r) {
    const int tt = t0 + wid * 4 + r;
    const float4* xg = (const float4*)(x + (size_t)tt * DD);
    float4* sxv = (float4*)sx[wid];
    ushort4* xbv = (ushort4*)(xb + (size_t)tt * DD);
#pragma unroll
    for (int i = 0; i < 4; ++i) {
      float4 v = xg[i * 64 + lane];
      sxv[i * 64 + lane] = v;
      ushort4 h;
      h.x = f2b(v.x); h.y = f2b(v.y); h.z = f2b(v.z); h.w = f2b(v.w);
      xbv[i * 64 + lane] = h;
    }
    asm volatile("s_waitcnt lgkmcnt(0)" ::: "memory");

    double part[8];
#pragma unroll
    for (int e = 0; e < 8; ++e) part[e] = 0.0;
#pragma unroll
    for (int c = 0; c < 16; ++c) {
      const double xd = (double)sx[wid][c * 64 + lane];
#pragma unroll
      for (int e = 0; e < 8; ++e)
        part[e] += xd * (double)sgwt[e * DD + c * 64 + lane];
    }
#pragma unroll
    for (int off = 1; off < 64; off <<= 1) {
#pragma unroll
      for (int e = 0; e < 8; ++e) part[e] += __shfl_xor(part[e], off);
    }
    if (lane == 0) {
      double lg[8];
#pragma unroll
      for (int i = 0; i < 8; ++i) lg[i] = part[i] + (double)gb[i];
      int e1 = 0; double m1 = lg[0];
#pragma unroll
      for (int i = 1; i < 8; ++i) if (lg[i] > m1) { m1 = lg[i]; e1 = i; }
      int e2 = 0; double m2 = -1.0e300;
#pragma unroll
      for (int i = 0; i < 8; ++i) if (i != e1 && lg[i] > m2) { m2 = lg[i]; e2 = i; }
      se1[wid * 4 + r] = e1;
      se2[wid * 4 + r] = e2;
    }
  }
  __syncthreads();

  if (tid < EN) {
    int cnt = 0;
#pragma unroll
    for (int i = 0; i < 16; ++i) cnt += (se1[i] == tid) + (se2[i] == tid);
    int base = atomicAdd(&counts[tid * CPAD], cnt);
    int* dst = lists + tid * T_TOK;
    for (int i = 0; i < 16; ++i) {
      if (se1[i] == tid) {
        if (WRITE_PIDX) pidx[2 * (t0 + i)] = tid * T_TOK + base;
        dst[base++] = t0 + i;
      }
      if (se2[i] == tid) {
        if (WRITE_PIDX) pidx[2 * (t0 + i) + 1] = tid * T_TOK + base;
        dst[base++] = t0 + i;
      }
    }
  }
}

// ---------- Phase 3: 256x256 GEMM, BK=64, 8 waves, 2-phase counted-vmcnt pipeline ----------
// Rationale: 2x arithmetic intensity vs 128^2 (64 MFMA/wave per 64KB staged) makes the
// counted-vmcnt pipeline pay (R12's 128^2 attempt lost on this ratio). Per K-tile:
//   P0: STAGE_A(next) ; vmcnt(4) [retires current tile's 8, leaves 4 in flight] ;
//       raw s_barrier ; ds_read kk0 ; 32 MFMA
//   P1: STAGE_B(next) ; ds_read kk1 ; 32 MFMA ; raw s_barrier [protects buffer
//       overwritten by NEXT iter's STAGE_A = the buffer read this iter]
// All pieces session-verified: R4 256^2 decomposition/epilogue, R10 swizzle (0 confl),
// R12 vmcnt/raw-barrier correctness pattern. VGPR ~200: NO min-wave launch_bounds (R7).
template <bool ATOMIC>
__global__ __launch_bounds__(512) void expert_gemm_kernel(
    const uint16_t* __restrict__ xb, const uint16_t* __restrict__ wt,
    const float* __restrict__ eb, const int* __restrict__ counts,
    const int* __restrict__ lists, uint16_t* __restrict__ dst,
    float* __restrict__ dstf) {
  const int orig = blockIdx.x;
  const int e = orig & 7;               // expert == XCD
  const int rem = orig >> 3;            // 0..127
  const int m0 = (rem >> 2) * BM;
  const int n0 = (rem & 3) * BN;
  const int cnt = counts[e * CPAD];
  if (m0 >= cnt) return;
  int rows = cnt - m0; if (rows > BM) rows = BM;
  int offsE = 0;
  if (!ATOMIC) {
#pragma unroll
    for (int i = 0; i < EN; ++i) offsE += (i < e) ? counts[i * CPAD] : 0;
  }

  __shared__ uint16_t sA[2 * BM * BK];  // 64 KB dbuf
  __shared__ uint16_t sB[2 * BN * BK];  // 64 KB dbuf
  __shared__ int toks[BM];

  const int tid = threadIdx.x;
  if (tid < BM) {
    int rr = tid < rows ? tid : 0;
    toks[tid] = lists[e * T_TOK + m0 + rr];
  }
  __syncthreads();

  const int lane = tid & 63;
  const int wid = tid >> 6;        // 0..7
  const int wm = wid >> 2;         // 0..1 (128-row half)
  const int wn = wid & 3;          // 0..3 (64-col quarter)

  v4f acc[8][4];
#pragma unroll
  for (int i = 0; i < 8; ++i)
#pragma unroll
    for (int j = 0; j < 4; ++j) acc[i][j] = (v4f){0.f, 0.f, 0.f, 0.f};

  // Staging: slot idx = i*512+tid (i<4 per matrix); row = i*64+(tid>>3); chunk = idx&7.
  // koff iteration-invariant: row&7 = (tid>>3)&7 (i*64 ≡ 0 mod 8). Same algebra as R10.
  const int koff = (((tid & 7) ^ ((tid >> 3) & 7)) << 3);
  const uint16_t* wte = wt + ((size_t)e << 20) + (size_t)n0 * DD;
  const uint16_t* aptr[4];
  const uint16_t* bptr[4];
#pragma unroll
  for (int i = 0; i < 4; ++i) {
    int row = i * 64 + (tid >> 3);
    aptr[i] = xb + (size_t)toks[row] * DD + koff;
    bptr[i] = wte + (size_t)row * DD + koff;
  }

#define STAGE_A(buf, k0)                                                        \
  {                                                                             \
    _Pragma("unroll")                                                           \
    for (int i = 0; i < 4; ++i) {                                               \
      int idx = i * 512 + tid;                                                  \
      __builtin_amdgcn_global_load_lds(                                         \
          (const AS1 uint32_t*)(aptr[i] + (k0)),                                \
          (AS3 uint32_t*)(sA + (buf) * (BM * BK) + idx * 8), 16, 0, 0);         \
    }                                                                           \
  }
#define STAGE_B(buf, k0)                                                        \
  {                                                                             \
    _Pragma("unroll")                                                           \
    for (int i = 0; i < 4; ++i) {                                               \
      int idx = i * 512 + tid;                                                  \
      __builtin_amdgcn_global_load_lds(                                         \
          (const AS1 uint32_t*)(bptr[i] + (k0)),                                \
          (AS3 uint32_t*)(sB + (buf) * (BN * BK) + idx * 8), 16, 0, 0);         \
    }                                                                           \
  }

  const int c0 = lane >> 4;        // k-subchunk 0..3
  const int rsel = lane & 15;
  const int rx = lane & 7;         // = row&7 for all fragment rows

  STAGE_A(0, 0);
  STAGE_B(0, 0);
  int cur = 0;
  for (int kt = 0; kt < NT; ++kt) {
    const int k1 = (kt + 1) * BK;
    const bool next = (kt + 1 < NT);

    // ---- phase 0: issue next-A, retire current tile, compute kk=0 ----
    if (next) {
      STAGE_A(cur ^ 1, k1);                        // 4 loads, stay in flight
      __builtin_amdgcn_sched_barrier(0);
      asm volatile("s_waitcnt vmcnt(4)" ::: "memory");  // current tile's 8 retired
    } else {
      __builtin_amdgcn_sched_barrier(0);
      asm volatile("s_waitcnt vmcnt(0)" ::: "memory");  // last tile: full drain
    }
    __builtin_amdgcn_sched_barrier(0);
    __builtin_amdgcn_s_barrier();                  // all waves retired -> LDS complete
    __builtin_amdgcn_sched_barrier(0);

    const uint16_t* a_base = sA + cur * (BM * BK);
    const uint16_t* b_base = sB + cur * (BN * BK);
    {
      v8bf af[8], bfr[4];
#pragma unroll
      for (int m = 0; m < 8; ++m) {
        int row_a = wm * 128 + m * 16 + rsel;
        af[m] = *(const v8bf*)(a_base + row_a * BK + ((c0 ^ rx) << 3));
      }
#pragma unroll
      for (int n = 0; n < 4; ++n) {
        int row_b = wn * 64 + n * 16 + rsel;
        bfr[n] = *(const v8bf*)(b_base + row_b * BK + ((c0 ^ rx) << 3));
      }
      __builtin_amdgcn_s_setprio(1);
#pragma unroll
      for (int m = 0; m < 8; ++m)
#pragma unroll
        for (int n = 0; n < 4; ++n)
          acc[m][n] = __builtin_amdgcn_mfma_f32_16x16x32_bf16(
              af[m], bfr[n], acc[m][n], 0, 0, 0);
      __builtin_amdgcn_s_setprio(0);
    }

    // ---- phase 1: issue next-B, compute kk=1, close the buffer ----
    if (next) STAGE_B(cur ^ 1, k1);
    __builtin_amdgcn_sched_barrier(0);
    {
      v8bf af[8], bfr[4];
#pragma unroll
      for (int m = 0; m < 8; ++m) {
        int row_a = wm * 128 + m * 16 + rsel;
        af[m] = *(const v8bf*)(a_base + row_a * BK + (((4 + c0) ^ rx) << 3));
      }
#pragma unroll
      for (int n = 0; n < 4; ++n) {
        int row_b = wn * 64 + n * 16 + rsel;
        bfr[n] = *(const v8bf*)(b_base + row_b * BK + (((4 + c0) ^ rx) << 3));
      }
      __builtin_amdgcn_s_setprio(1);
#pragma unroll
      for (int m = 0; m < 8; ++m)
#pragma unroll
        for (int n = 0; n < 4; ++n)
          acc[m][n] = __builtin_amdgcn_mfma_f32_16x16x32_bf16(
              af[m], bfr[n], acc[m][n], 0, 0, 0);
      __builtin_amdgcn_s_setprio(0);
    }
    __builtin_amdgcn_sched_barrier(0);
    __builtin_amdgcn_s_barrier();    // all waves done reading buf[cur]; next iter's
    __builtin_amdgcn_sched_barrier(0);  // STAGE_A overwrites it
    cur ^= 1;
  }
#undef STAGE_A
#undef STAGE_B

  // Epilogue (R4-verified 256^2 indexing): C/D layout col=lane&15, row=(lane>>4)*4+j.
  const int col = lane & 15, rq = lane >> 4;
  if (!ATOMIC) {
    uint16_t* base = dst + (size_t)(offsE + m0) * DD + n0 + wn * 64 + col;
#pragma unroll
    for (int m = 0; m < 8; ++m) {
#pragma unroll
      for (int j = 0; j < 4; ++j) {
        int trow = wm * 128 + m * 16 + rq * 4 + j;
        if (trow < rows) {
          uint16_t* orow = base + (size_t)trow * DD;
#pragma unroll
          for (int n = 0; n < 4; ++n) orow[n * 16] = f2b(acc[m][n][j]);
        }
      }
    }
  } else {
    float biasv[4];
#pragma unroll
    for (int n = 0; n < 4; ++n)
      biasv[n] = eb[e * DD + n0 + wn * 64 + n * 16 + col];
#pragma unroll
    for (int m = 0; m < 8; ++m) {
#pragma unroll
      for (int j = 0; j < 4; ++j) {
        int trow = wm * 128 + m * 16 + rq * 4 + j;
        if (trow < rows) {
          float* orow = dstf + (size_t)toks[trow] * DD + n0;
#pragma unroll
          for (int n = 0; n < 4; ++n)
            atomicAdd(orow + wn * 64 + n * 16 + col, acc[m][n][j] + biasv[n]);
        }
      }
    }
  }
}

// ---------- Phase 4: combine — R15-identical ----------
__global__ __launch_bounds__(256) void combine_kernel(
    const uint16_t* __restrict__ wsO, const int* __restrict__ pidx,
    const int* __restrict__ counts, const float* __restrict__ eb,
    float* __restrict__ out) {
  __shared__ int soff[EN];
  const int tid = threadIdx.x;
  if (tid == 0) {
    int o = 0;
#pragma unroll
    for (int i = 0; i < EN; ++i) { soff[i] = o; o += counts[i * CPAD]; }
  }
  __syncthreads();
  const int t0 = blockIdx.x * 4;
#pragma unroll
  for (int r = 0; r < 4; ++r) {
    const int t = t0 + r;
    const int pi1 = pidx[2 * t], pi2 = pidx[2 * t + 1];
    const int e1 = pi1 >> 13, p1 = pi1 & (T_TOK - 1);
    const int e2 = pi2 >> 13, p2 = pi2 & (T_TOK - 1);
    ushort4 r1 = ((const ushort4*)(wsO + (size_t)(soff[e1] + p1) * DD))[tid];
    ushort4 r2 = ((const ushort4*)(wsO + (size_t)(soff[e2] + p2) * DD))[tid];
    v4f b1 = ((const v4f*)(eb + e1 * DD))[tid];
    v4f b2 = ((const v4f*)(eb + e2 * DD))[tid];
    v4f o;
    o[0] = b2f(r1.x) + b2f(r2.x) + b1[0] + b2[0];
    o[1] = b2f(r1.y) + b2f(r2.y) + b1[1] + b2[1];
    o[2] = b2f(r1.z) + b2f(r2.z) + b1[2] + b2[2];
    o[3] = b2f(r1.w) + b2f(r2.w) + b1[3] + b2[3];
    ((v4f*)(out + (size_t)t * DD))[tid] = o;
  }
}

extern "C" void kernel_launch(void* const* d_in, const int* in_sizes, int n_in,
                              void* d_out, int out_size, void* d_ws, size_t ws_size,
                              hipStream_t stream) {
  const float* x  = (const float*)d_in[0];   // [4,2048,1024] f32
  const float* gw = (const float*)d_in[1];   // [1024,8] f32
  const float* gb = (const float*)d_in[2];   // [8] f32
  const float* ew = (const float*)d_in[3];   // [8,1024,1024] f32
  const float* ebias = (const float*)d_in[4];// [8,1024] f32
  float* out = (float*)d_out;                // [4,2048,1024] f32

  uint8_t* ws = (uint8_t*)d_ws;
  int* counts = (int*)ws;                                    // 512 B
  int* lists  = (int*)(ws + 512);                            // 256 KiB
  int* pidx   = (int*)(ws + 512 + 262144);                   // 64 KiB
  uint16_t* xb = (uint16_t*)(ws + 512 + 262144 + 65536);     // 16 MiB
  uint16_t* wt = (uint16_t*)(ws + 512 + 262144 + 65536 + 16777216); // 16 MiB
  uint16_t* wsO = (uint16_t*)(ws + 512 + 262144 + 65536 + 2 * 16777216); // 32 MiB bf16
  const size_t need = 512ull + 262144 + 65536 + 2 * 16777216 +
                      (size_t)2 * T_TOK * DD * sizeof(uint16_t);
  const bool use_ws = ws_size >= need;

  hipMemsetAsync(counts, 0, 512, stream);
  if (use_ws) {
    prep_kernel<true><<<GATE_NB + 2048, 256, 49408, stream>>>(
        x, gw, gb, xb, counts, lists, pidx, ew, wt);
    expert_gemm_kernel<false><<<NWG, 512, 0, stream>>>(
        xb, wt, ebias, counts, lists, wsO, nullptr);
    combine_kernel<<<T_TOK / 4, 256, 0, stream>>>(wsO, pidx, counts, ebias, out);
  } else {
    hipMemsetAsync(d_out, 0, (size_t)out_size * sizeof(float), stream);
    prep_kernel<false><<<GATE_NB + 2048, 256, 49408, stream>>>(
        x, gw, gb, xb, counts, lists, pidx, ew, wt);
    expert_gemm_kernel<true><<<NWG, 512, 0, stream>>>(
        xb, wt, ebias, counts, lists, nullptr, out);
  }
}

// Round 17
// 92.378 us; speedup vs baseline: 1.2422x; 1.2422x over previous
//
#include <hip/hip_runtime.h>
#include <stdint.h>

#define T_TOK 8192   // B*S
#define DD    1024   // D
#define EN    8      // experts
#define CPAD  16     // ints per expert counter slot (64 B each)

#define BM 128
#define BN 128
#define BK 64
#define NT (DD / BK)   // 16 K-steps
#define NWG 4096       // 8 experts * 64 M-slots * 8 N-tiles (early-exit)

#define GATE_NB 512    // gate blocks (16 tokens each)

#define AS1 __attribute__((address_space(1)))
#define AS3 __attribute__((address_space(3)))

typedef __bf16 v8bf __attribute__((ext_vector_type(8)));
typedef float  v4f  __attribute__((ext_vector_type(4)));

__device__ __forceinline__ uint16_t f2b(float f) {
  uint32_t u = __builtin_bit_cast(uint32_t, f);
  u += 0x7FFFu + ((u >> 16) & 1u);          // round-to-nearest-even
  return (uint16_t)(u >> 16);
}
__device__ __forceinline__ float b2f(uint16_t h) {
  uint32_t u = (uint32_t)h << 16;
  return __builtin_bit_cast(float, u);
}

// ---------- Phase 1 (fused): gate blocks [0,512), transpose [512,2560) ----------
// R11 prep verbatim — best measured. R13 (more blocks), R14 (register-resident x),
// R16 (deep-pipeline gemm) all regressed; this is the session optimum.
template <bool WRITE_PIDX>
__global__ __launch_bounds__(256) void prep_kernel(
    const float* __restrict__ x, const float* __restrict__ gw,
    const float* __restrict__ gb, uint16_t* __restrict__ xb,
    int* __restrict__ counts, int* __restrict__ lists, int* __restrict__ pidx,
    const float* __restrict__ w, uint16_t* __restrict__ wt) {
  extern __shared__ __align__(16) uint8_t smem[];
  const int bid = blockIdx.x;
  const int tid = threadIdx.x;

  if (bid >= GATE_NB) {             // ---- transpose part ----
    float (*tile)[65] = (float(*)[65])smem;   // 16.6 KB
    const int tb = bid - GATE_NB;
    const int e = tb >> 8;
    const int rem = tb & 255;
    const int f0 = (rem & 15) * 64, d0 = (rem >> 4) * 64;
    const float* wsrc = w + ((size_t)e << 20);
    uint16_t* wdst = wt + ((size_t)e << 20);
    const int r4 = tid >> 4;          // 0..15
    const int c4 = (tid & 15) * 4;    // 0,4,...,60
#pragma unroll
    for (int i = 0; i < 4; ++i) {
      int row = i * 16 + r4;
      const float4 v = *(const float4*)(wsrc + (size_t)(d0 + row) * DD + f0 + c4);
      tile[row][c4 + 0] = v.x; tile[row][c4 + 1] = v.y;
      tile[row][c4 + 2] = v.z; tile[row][c4 + 3] = v.w;
    }
    __syncthreads();
#pragma unroll
    for (int i = 0; i < 4; ++i) {
      int f = i * 16 + r4;
      ushort4 h;
      h.x = f2b(tile[c4 + 0][f]); h.y = f2b(tile[c4 + 1][f]);
      h.z = f2b(tile[c4 + 2][f]); h.w = f2b(tile[c4 + 3][f]);
      *(ushort4*)(wdst + (size_t)(f0 + f) * DD + d0 + c4) = h;
    }
    return;
  }

  // ---- gate part: 16 tokens per block, 4 per wave ----
  float* sgwt = (float*)smem;                      // 32 KB, transposed [e][1024]
  float (*sx)[DD] = (float(*)[DD])(smem + 32768);  // 16 KB, one token per wave
  int* se1 = (int*)(smem + 49152);                 // 16 ints
  int* se2 = (int*)(smem + 49152 + 64);

  // Fill sgwt: gw flat j = d*8+e -> sgwt[e*1024+d]. float4 spans 4 e's of one d.
#pragma unroll
  for (int i = 0; i < 8; ++i) {
    const int j4 = i * 256 + tid;
    const float4 v = ((const float4*)gw)[j4];
    const int d = j4 >> 1;
    const int e0 = (j4 & 1) * 4;
    sgwt[(e0 + 0) * DD + d] = v.x;
    sgwt[(e0 + 1) * DD + d] = v.y;
    sgwt[(e0 + 2) * DD + d] = v.z;
    sgwt[(e0 + 3) * DD + d] = v.w;
  }
  __syncthreads();

  const int t0 = bid * 16;
  const int wid = tid >> 6, lane = tid & 63;

  for (int r = 0; r < 4; ++r) {
    const int tt = t0 + wid * 4 + r;
    const float4* xg = (const float4*)(x + (size_t)tt * DD);
    float4* sxv = (float4*)sx[wid];
    ushort4* xbv = (ushort4*)(xb + (size_t)tt * DD);
#pragma unroll
    for (int i = 0; i < 4; ++i) {
      float4 v = xg[i * 64 + lane];
      sxv[i * 64 + lane] = v;
      ushort4 h;
      h.x = f2b(v.x); h.y = f2b(v.y); h.z = f2b(v.z); h.w = f2b(v.w);
      xbv[i * 64 + lane] = h;
    }
    // Wave-local visibility: LDS per-wave is in-order; drain ds_writes before reads.
    asm volatile("s_waitcnt lgkmcnt(0)" ::: "memory");

    double part[8];
#pragma unroll
    for (int e = 0; e < 8; ++e) part[e] = 0.0;
#pragma unroll
    for (int c = 0; c < 16; ++c) {
      const double xd = (double)sx[wid][c * 64 + lane];
#pragma unroll
      for (int e = 0; e < 8; ++e)
        part[e] += xd * (double)sgwt[e * DD + c * 64 + lane];
    }
#pragma unroll
    for (int off = 1; off < 64; off <<= 1) {
#pragma unroll
      for (int e = 0; e < 8; ++e) part[e] += __shfl_xor(part[e], off);
    }
    if (lane == 0) {
      double lg[8];
#pragma unroll
      for (int i = 0; i < 8; ++i) lg[i] = part[i] + (double)gb[i];
      int e1 = 0; double m1 = lg[0];
#pragma unroll
      for (int i = 1; i < 8; ++i) if (lg[i] > m1) { m1 = lg[i]; e1 = i; }
      int e2 = 0; double m2 = -1.0e300;
#pragma unroll
      for (int i = 0; i < 8; ++i) if (i != e1 && lg[i] > m2) { m2 = lg[i]; e2 = i; }
      se1[wid * 4 + r] = e1;
      se2[wid * 4 + r] = e2;
    }
  }
  __syncthreads();

  if (tid < EN) {
    int cnt = 0;
#pragma unroll
    for (int i = 0; i < 16; ++i) cnt += (se1[i] == tid) + (se2[i] == tid);
    int base = atomicAdd(&counts[tid * CPAD], cnt);
    int* dst = lists + tid * T_TOK;
    for (int i = 0; i < 16; ++i) {
      if (se1[i] == tid) {
        if (WRITE_PIDX) pidx[2 * (t0 + i)] = tid * T_TOK + base;
        dst[base++] = t0 + i;
      }
      if (se2[i] == tid) {
        if (WRITE_PIDX) pidx[2 * (t0 + i) + 1] = tid * T_TOK + base;
        dst[base++] = t0 + i;
      }
    }
  }
}

// ---------- Phase 3: gathered per-expert GEMM — R10-verified config, verbatim ----------
// m97 structure: 128x128, BK=64, single buffer, 4 waves, 4 blocks/CU (16 waves/CU).
// 30% MfmaUtil, 0 conflicts, FETCH == unique bytes (4x reproduced: R10/R13/R15).
// Schedule rewrites (R12 counted-vmcnt dbuf, R16 256^2 2-phase) both regressed:
// cross-block overlap at 4 blk/CU beats in-block pipelining at <=2 blk/CU.
template <bool ATOMIC>
__global__ __launch_bounds__(256, 4) void expert_gemm_kernel(
    const uint16_t* __restrict__ xb, const uint16_t* __restrict__ wt,
    const float* __restrict__ eb, const int* __restrict__ counts,
    const int* __restrict__ lists, uint16_t* __restrict__ dst,
    float* __restrict__ dstf) {
  const int orig = blockIdx.x;
  const int e = orig & 7;               // expert == XCD
  const int rem = orig >> 3;            // 0..511
  const int m0 = (rem >> 3) * BM;
  const int n0 = (rem & 7) * BN;
  const int cnt = counts[e * CPAD];
  if (m0 >= cnt) return;
  int rows = cnt - m0; if (rows > BM) rows = BM;
  int offsE = 0;
  if (!ATOMIC) {
#pragma unroll
    for (int i = 0; i < EN; ++i) offsE += (i < e) ? counts[i * CPAD] : 0;
  }

  __shared__ uint16_t sA[BM * BK];  // 16 KB single buffer
  __shared__ uint16_t sB[BN * BK];  // 16 KB
  __shared__ int toks[BM];

  const int tid = threadIdx.x;
  if (tid < BM) {
    int rr = tid < rows ? tid : 0;
    toks[tid] = lists[e * T_TOK + m0 + rr];
  }
  __syncthreads();

  const int lane = tid & 63;
  const int wid = tid >> 6;        // 0..3
  const int wm = wid >> 1;         // 0..1 (64 rows)
  const int wn = wid & 1;          // 0..1 (64 cols)

  v4f acc[4][4];
#pragma unroll
  for (int i = 0; i < 4; ++i)
#pragma unroll
    for (int j = 0; j < 4; ++j) acc[i][j] = (v4f){0.f, 0.f, 0.f, 0.f};

  const int koff = (((tid & 7) ^ ((tid >> 3) & 7)) << 3);
  const uint16_t* wte = wt + ((size_t)e << 20) + (size_t)n0 * DD;
  const uint16_t* aptr[4];
  const uint16_t* bptr[4];
#pragma unroll
  for (int i = 0; i < 4; ++i) {
    int row = i * 32 + (tid >> 3);
    aptr[i] = xb + (size_t)toks[row] * DD + koff;
    bptr[i] = wte + (size_t)row * DD + koff;
  }

  const int c0 = lane >> 4;        // k-subchunk 0..3
  const int rsel = lane & 15;
  const int rx = lane & 7;         // = row&7 for all fragment rows

  for (int kt = 0; kt < NT; ++kt) {
    const int k0 = kt * BK;
#pragma unroll
    for (int i = 0; i < 4; ++i) {
      int idx = i * 256 + tid;
      __builtin_amdgcn_global_load_lds(
          (const AS1 uint32_t*)(aptr[i] + k0),
          (AS3 uint32_t*)(sA + idx * 8), 16, 0, 0);
      __builtin_amdgcn_global_load_lds(
          (const AS1 uint32_t*)(bptr[i] + k0),
          (AS3 uint32_t*)(sB + idx * 8), 16, 0, 0);
    }
    __syncthreads();   // vmcnt(0) drain before barrier: staged data visible

#pragma unroll
    for (int kk = 0; kk < 2; ++kk) {
      v8bf af[4], bfr[4];
#pragma unroll
      for (int m = 0; m < 4; ++m) {
        int row_a = wm * 64 + m * 16 + rsel;
        af[m] = *(const v8bf*)(sA + row_a * BK + (((kk * 4 + c0) ^ rx) << 3));
      }
#pragma unroll
      for (int n = 0; n < 4; ++n) {
        int row_b = wn * 64 + n * 16 + rsel;
        bfr[n] = *(const v8bf*)(sB + row_b * BK + (((kk * 4 + c0) ^ rx) << 3));
      }
#pragma unroll
      for (int m = 0; m < 4; ++m)
#pragma unroll
        for (int n = 0; n < 4; ++n)
          acc[m][n] = __builtin_amdgcn_mfma_f32_16x16x32_bf16(
              af[m], bfr[n], acc[m][n], 0, 0, 0);
    }
    __syncthreads();   // protect buffer before next STAGE overwrites
  }

  // Epilogue: C/D layout col=lane&15, row=(lane>>4)*4+j.
  const int col = lane & 15, rq = lane >> 4;
  if (!ATOMIC) {
    uint16_t* base = dst + (size_t)(offsE + m0) * DD + n0 + wn * 64 + col;
#pragma unroll
    for (int m = 0; m < 4; ++m) {
#pragma unroll
      for (int j = 0; j < 4; ++j) {
        int trow = wm * 64 + m * 16 + rq * 4 + j;
        if (trow < rows) {
          uint16_t* orow = base + (size_t)trow * DD;
#pragma unroll
          for (int n = 0; n < 4; ++n) orow[n * 16] = f2b(acc[m][n][j]);
        }
      }
    }
  } else {
    float biasv[4];
#pragma unroll
    for (int n = 0; n < 4; ++n)
      biasv[n] = eb[e * DD + n0 + wn * 64 + n * 16 + col];
#pragma unroll
    for (int m = 0; m < 4; ++m) {
#pragma unroll
      for (int j = 0; j < 4; ++j) {
        int trow = wm * 64 + m * 16 + rq * 4 + j;
        if (trow < rows) {
          float* orow = dstf + (size_t)toks[trow] * DD + n0;
#pragma unroll
          for (int n = 0; n < 4; ++n)
            atomicAdd(orow + wn * 64 + n * 16 + col, acc[m][n][j] + biasv[n]);
        }
      }
    }
  }
}

// ---------- Phase 4: combine — out[t] = wsO[row(e1,p1)] + wsO[row(e2,p2)] + b1 + b2 ----------
__global__ __launch_bounds__(256) void combine_kernel(
    const uint16_t* __restrict__ wsO, const int* __restrict__ pidx,
    const int* __restrict__ counts, const float* __restrict__ eb,
    float* __restrict__ out) {
  __shared__ int soff[EN];
  const int tid = threadIdx.x;
  if (tid == 0) {
    int o = 0;
#pragma unroll
    for (int i = 0; i < EN; ++i) { soff[i] = o; o += counts[i * CPAD]; }
  }
  __syncthreads();
  const int t0 = blockIdx.x * 4;
#pragma unroll
  for (int r = 0; r < 4; ++r) {
    const int t = t0 + r;
    const int pi1 = pidx[2 * t], pi2 = pidx[2 * t + 1];
    const int e1 = pi1 >> 13, p1 = pi1 & (T_TOK - 1);
    const int e2 = pi2 >> 13, p2 = pi2 & (T_TOK - 1);
    ushort4 r1 = ((const ushort4*)(wsO + (size_t)(soff[e1] + p1) * DD))[tid];
    ushort4 r2 = ((const ushort4*)(wsO + (size_t)(soff[e2] + p2) * DD))[tid];
    v4f b1 = ((const v4f*)(eb + e1 * DD))[tid];
    v4f b2 = ((const v4f*)(eb + e2 * DD))[tid];
    v4f o;
    o[0] = b2f(r1.x) + b2f(r2.x) + b1[0] + b2[0];
    o[1] = b2f(r1.y) + b2f(r2.y) + b1[1] + b2[1];
    o[2] = b2f(r1.z) + b2f(r2.z) + b1[2] + b2[2];
    o[3] = b2f(r1.w) + b2f(r2.w) + b1[3] + b2[3];
    ((v4f*)(out + (size_t)t * DD))[tid] = o;
  }
}

extern "C" void kernel_launch(void* const* d_in, const int* in_sizes, int n_in,
                              void* d_out, int out_size, void* d_ws, size_t ws_size,
                              hipStream_t stream) {
  const float* x  = (const float*)d_in[0];   // [4,2048,1024] f32
  const float* gw = (const float*)d_in[1];   // [1024,8] f32
  const float* gb = (const float*)d_in[2];   // [8] f32
  const float* ew = (const float*)d_in[3];   // [8,1024,1024] f32
  const float* ebias = (const float*)d_in[4];// [8,1024] f32
  float* out = (float*)d_out;                // [4,2048,1024] f32

  uint8_t* ws = (uint8_t*)d_ws;
  int* counts = (int*)ws;                                    // 512 B
  int* lists  = (int*)(ws + 512);                            // 256 KiB
  int* pidx   = (int*)(ws + 512 + 262144);                   // 64 KiB
  uint16_t* xb = (uint16_t*)(ws + 512 + 262144 + 65536);     // 16 MiB
  uint16_t* wt = (uint16_t*)(ws + 512 + 262144 + 65536 + 16777216); // 16 MiB
  uint16_t* wsO = (uint16_t*)(ws + 512 + 262144 + 65536 + 2 * 16777216); // 32 MiB bf16
  const size_t need = 512ull + 262144 + 65536 + 2 * 16777216 +
                      (size_t)2 * T_TOK * DD * sizeof(uint16_t);
  const bool use_ws = ws_size >= need;

  hipMemsetAsync(counts, 0, 512, stream);
  if (use_ws) {
    prep_kernel<true><<<GATE_NB + 2048, 256, 49408, stream>>>(
        x, gw, gb, xb, counts, lists, pidx, ew, wt);
    expert_gemm_kernel<false><<<NWG, 256, 0, stream>>>(
        xb, wt, ebias, counts, lists, wsO, nullptr);
    combine_kernel<<<T_TOK / 4, 256, 0, stream>>>(wsO, pidx, counts, ebias, out);
  } else {
    hipMemsetAsync(d_out, 0, (size_t)out_size * sizeof(float), stream);
    prep_kernel<false><<<GATE_NB + 2048, 256, 49408, stream>>>(
        x, gw, gb, xb, counts, lists, pidx, ew, wt);
    expert_gemm_kernel<true><<<NWG, 256, 0, stream>>>(
        xb, wt, ebias, counts, lists, nullptr, out);
  }
}